// Round 7
// baseline (426.811 us; speedup 1.0000x reference)
//
#include <hip/hip_runtime.h>
#include <hip/hip_bf16.h>
#include <math.h>

#define NN 50000
#define NE 800000
#define NK 4
#define FD 128
#define CD 32
#define NCHUNK 196   // ceil(NN/256)
#define NBLK 782     // ceil(NN/64) gemm blocks / bn chunks

typedef unsigned short u16;

__device__ __forceinline__ u16 f2bf(float x) {
    union { float f; unsigned u; } c; c.f = x;
    unsigned r = c.u + 0x7fffu + ((c.u >> 16) & 1u);  // RNE
    return (u16)(r >> 16);
}
__device__ __forceinline__ float bflo(unsigned pair) {   // low bf16 of packed u32
    union { unsigned u; float f; } c; c.u = pair << 16;
    return c.f;
}
__device__ __forceinline__ float bfhi(unsigned pair) {   // high bf16 of packed u32
    union { unsigned u; float f; } c; c.u = pair & 0xffff0000u;
    return c.f;
}

// ---------------- CSR build ----------------

__global__ void k_count(const int* __restrict__ dst, int* __restrict__ count) {
    int i = blockIdx.x * 256 + threadIdx.x;
    if (i < NE) atomicAdd(&count[dst[i]], 1);
}

__global__ void k_chunksum(const int* __restrict__ count, int* __restrict__ csum) {
    __shared__ int s[256];
    int tid = threadIdx.x;
    int i = blockIdx.x * 256 + tid;
    s[tid] = (i < NN) ? count[i] : 0;
    __syncthreads();
    for (int off = 128; off > 0; off >>= 1) {
        if (tid < off) s[tid] += s[tid + off];
        __syncthreads();
    }
    if (tid == 0) csum[blockIdx.x] = s[0];
}

__global__ void k_scan_csum(int* __restrict__ csum) {
    __shared__ int s[256];
    int tid = threadIdx.x;
    int v = (tid < NCHUNK) ? csum[tid] : 0;
    s[tid] = v;
    __syncthreads();
    for (int off = 1; off < 256; off <<= 1) {
        int t = 0;
        if (tid >= off) t = s[tid - off];
        __syncthreads();
        s[tid] += t;
        __syncthreads();
    }
    if (tid < NCHUNK) csum[tid] = s[tid] - v;  // exclusive
}

__global__ void k_scan_final(const int* __restrict__ count, const int* __restrict__ csum,
                             int* __restrict__ rowstart, int* __restrict__ cursor) {
    __shared__ int s[256];
    int tid = threadIdx.x;
    int i = blockIdx.x * 256 + tid;
    int v = (i < NN) ? count[i] : 0;
    s[tid] = v;
    __syncthreads();
    for (int off = 1; off < 256; off <<= 1) {
        int t = 0;
        if (tid >= off) t = s[tid - off];
        __syncthreads();
        s[tid] += t;
        __syncthreads();
    }
    int incl = s[tid];
    int base = csum[blockIdx.x];
    int excl = base + incl - v;
    if (i < NN) {
        rowstart[i] = excl;
        cursor[i] = excl;
        if (i == NN - 1) rowstart[NN] = excl + v;
    }
}

// one packed scattered stream: {src, w01 (bf16 k0|k1), w23 (bf16 k2|k3), pad}
__global__ void k_scatter(const int* __restrict__ src, const int* __restrict__ dst,
                          const float* __restrict__ ew,
                          int* __restrict__ cursor, int4* __restrict__ sse) {
    int e = blockIdx.x * 256 + threadIdx.x;
    if (e < NE) {
        int d = dst[e];
        int p = atomicAdd(&cursor[d], 1);
        unsigned w01 = (unsigned)f2bf(ew[e]) | ((unsigned)f2bf(ew[(size_t)NE + e]) << 16);
        unsigned w23 = (unsigned)f2bf(ew[(size_t)2 * NE + e]) | ((unsigned)f2bf(ew[(size_t)3 * NE + e]) << 16);
        sse[p] = make_int4(src[e], (int)w01, (int)w23, 0);
    }
}

// ---------------- fused encoder + y0 (y0 stored bf16 [N][32]) ----------------

__global__ void __launch_bounds__(256) k_enc_y0(const float* __restrict__ x,
                                                const float* __restrict__ W,
                                                const float* __restrict__ b,
                                                const float* __restrict__ W1,
                                                float* __restrict__ out,
                                                u16* __restrict__ y0) {
    __shared__ float xsT[FD][68];
    int tid = threadIdx.x;
    int nbase = blockIdx.x * 64;

    int r = tid >> 2;
    int cg = (tid & 3) * 32;
    int gn = nbase + r;
    const float* xr = x + (size_t)(gn < NN ? gn : NN - 1) * FD;
#pragma unroll
    for (int q = 0; q < 8; ++q) {
        float4 v = *(const float4*)(xr + cg + q * 4);
        int f = cg + q * 4;
        xsT[f][r] = v.x; xsT[f + 1][r] = v.y; xsT[f + 2][r] = v.z; xsT[f + 3][r] = v.w;
    }
    __syncthreads();

    int cq = (tid & 31) * 4;
    int col = tid & 31;
    int g = tid >> 5;
    float acc[8][4];
    float acy[8];
#pragma unroll
    for (int i = 0; i < 8; ++i) {
        acy[i] = 0.f;
#pragma unroll
        for (int j = 0; j < 4; ++j) acc[i][j] = 0.f;
    }

    for (int f = 0; f < FD; ++f) {
        float4 wv = *(const float4*)(W + f * FD + cq);
        float w1 = W1[f * CD + col];
        float4 xa = *(const float4*)&xsT[f][g * 8];
        float4 xb = *(const float4*)&xsT[f][g * 8 + 4];
        float xn[8] = {xa.x, xa.y, xa.z, xa.w, xb.x, xb.y, xb.z, xb.w};
#pragma unroll
        for (int i = 0; i < 8; ++i) {
            acc[i][0] += xn[i] * wv.x;
            acc[i][1] += xn[i] * wv.y;
            acc[i][2] += xn[i] * wv.z;
            acc[i][3] += xn[i] * wv.w;
            acy[i] += xn[i] * w1;
        }
    }
    float4 bv = *(const float4*)(b + cq);
#pragma unroll
    for (int i = 0; i < 8; ++i) {
        int n = nbase + g * 8 + i;
        if (n < NN) {
            float4 o;
            o.x = acc[i][0] + bv.x;
            o.y = acc[i][1] + bv.y;
            o.z = acc[i][2] + bv.z;
            o.w = acc[i][3] + bv.w;
            *(float4*)(out + (size_t)n * FD + cq) = o;
            y0[(size_t)n * CD + col] = f2bf(acy[i]);
        }
    }
}

// ---------------- aggregation + relu -> t bf16 [N][128] ----------------
// wave = node; HALF-WAVE per edge (2 edges per pass).
// lane: hi = lane>>5 (edge of pair), k = (lane&31)>>3, fq = lane&7 (feat quad).
// per lane per edge: uint2 gather (4 bf16 feats), 4 FMA. Combine halves via shfl_xor(32).

template <int STRIDE>
__global__ void __launch_bounds__(256) k_aggr(const u16* __restrict__ y,
                                              const int* __restrict__ row,
                                              const int4* __restrict__ sse,
                                              const float* __restrict__ b1,
                                              u16* __restrict__ tout) {
    int tid = threadIdx.x;
    int w = tid >> 6;
    int lane = tid & 63;
    int node = blockIdx.x * 4 + w;   // NN divisible by 4

    int hi = lane >> 5;
    int sub = lane & 31;
    int k = sub >> 3;
    int fq = sub & 7;
    int f0 = fq * 4;
    int col = (STRIDE == CD) ? f0 : (k * CD + f0);
    const u16* yb = y + col;

    bool klow = k < 2;
    int lsh = (k & 1) ? 0 : 16;

    float a0 = 0.f, a1 = 0.f, a2 = 0.f, a3 = 0.f;
    int beg = row[node], end = row[node + 1];
    for (int j0 = beg; j0 < end; j0 += 8) {
        int ssv[4];
        float wwv[4];
#pragma unroll
        for (int q = 0; q < 4; ++q) {
            int jj = j0 + q * 2 + hi;
            bool ok = jj < end;
            int jc = ok ? jj : beg;
            int4 ee = sse[jc];
            ssv[q] = ee.x;
            unsigned wp = klow ? (unsigned)ee.y : (unsigned)ee.z;
            unsigned wb = (wp << lsh) & 0xffff0000u;
            union { unsigned u; float f; } cv; cv.u = wb;
            wwv[q] = ok ? cv.f : 0.f;
        }
#pragma unroll
        for (int q = 0; q < 4; ++q) {
            uint2 pv = *(const uint2*)(yb + (size_t)ssv[q] * STRIDE);
            float wq = wwv[q];
            a0 += wq * bflo(pv.x);
            a1 += wq * bfhi(pv.x);
            a2 += wq * bflo(pv.y);
            a3 += wq * bfhi(pv.y);
        }
    }
    a0 += __shfl_xor(a0, 32);
    a1 += __shfl_xor(a1, 32);
    a2 += __shfl_xor(a2, 32);
    a3 += __shfl_xor(a3, 32);

    uint2 hv = *(const uint2*)(yb + (size_t)node * STRIDE);
    float4 bv = *(const float4*)(b1 + f0);
    float t0 = fmaxf(bflo(hv.x) + a0 + bv.x, 0.f);
    float t1 = fmaxf(bfhi(hv.x) + a1 + bv.y, 0.f);
    float t2 = fmaxf(bflo(hv.y) + a2 + bv.z, 0.f);
    float t3 = fmaxf(bfhi(hv.y) + a3 + bv.w, 0.f);
    if (hi == 0) {
        unsigned lo = (unsigned)f2bf(t0) | ((unsigned)f2bf(t1) << 16);
        unsigned h2 = (unsigned)f2bf(t2) | ((unsigned)f2bf(t3) << 16);
        *(uint2*)(tout + (size_t)node * FD + k * CD + f0) = make_uint2(lo, h2);
    }
}

// ---------------- MLP2 GEMM (t bf16 [N][128] -> u fp32 [4][N][32]) + BN partial sums ----------------

__global__ void __launch_bounds__(256) k_mlp2(const u16* __restrict__ t,
                                              const float* __restrict__ W2,
                                              const float* __restrict__ b2,
                                              float* __restrict__ u,
                                              float* __restrict__ part) {
    __shared__ float hsT[FD][68];
    __shared__ float sh1[8][32][4], sh2[8][32][4];
    int tid = threadIdx.x;
    int nbase = blockIdx.x * 64;

    int r = tid >> 2;
    int cg = (tid & 3) * 32;
    int gn = nbase + r;
    const u16* tr = t + (size_t)(gn < NN ? gn : NN - 1) * FD + cg;
#pragma unroll
    for (int q = 0; q < 4; ++q) {
        uint4 v = *(const uint4*)(tr + q * 8);
        int f = cg + q * 8;
        hsT[f + 0][r] = bflo(v.x); hsT[f + 1][r] = bfhi(v.x);
        hsT[f + 2][r] = bflo(v.y); hsT[f + 3][r] = bfhi(v.y);
        hsT[f + 4][r] = bflo(v.z); hsT[f + 5][r] = bfhi(v.z);
        hsT[f + 6][r] = bflo(v.w); hsT[f + 7][r] = bfhi(v.w);
    }
    __syncthreads();

    int c0 = (tid & 31) * 4;
    int g = tid >> 5;
    int kc = c0 >> 5, jb = c0 & 31;
    float acc[8][4];
#pragma unroll
    for (int i = 0; i < 8; ++i)
#pragma unroll
        for (int j = 0; j < 4; ++j) acc[i][j] = 0.f;

    for (int m = 0; m < CD; ++m) {
        float4 wv = *(const float4*)(W2 + m * CD + jb);
        float4 xa = *(const float4*)&hsT[kc * CD + m][g * 8];
        float4 xb = *(const float4*)&hsT[kc * CD + m][g * 8 + 4];
        float xn[8] = {xa.x, xa.y, xa.z, xa.w, xb.x, xb.y, xb.z, xb.w};
#pragma unroll
        for (int i = 0; i < 8; ++i) {
            acc[i][0] += xn[i] * wv.x;
            acc[i][1] += xn[i] * wv.y;
            acc[i][2] += xn[i] * wv.z;
            acc[i][3] += xn[i] * wv.w;
        }
    }
    float4 b2v = *(const float4*)(b2 + jb);
    float s1[4] = {0.f, 0.f, 0.f, 0.f};
    float s2[4] = {0.f, 0.f, 0.f, 0.f};
#pragma unroll
    for (int i = 0; i < 8; ++i) {
        int n = nbase + g * 8 + i;
        if (n < NN) {
            float4 o;
            o.x = acc[i][0] + b2v.x;
            o.y = acc[i][1] + b2v.y;
            o.z = acc[i][2] + b2v.z;
            o.w = acc[i][3] + b2v.w;
            *(float4*)(u + ((size_t)kc * NN + n) * CD + jb) = o;
            s1[0] += o.x; s2[0] += o.x * o.x;
            s1[1] += o.y; s2[1] += o.y * o.y;
            s1[2] += o.z; s2[2] += o.z * o.z;
            s1[3] += o.w; s2[3] += o.w * o.w;
        }
    }
    int cq = tid & 31;
#pragma unroll
    for (int j = 0; j < 4; ++j) { sh1[g][cq][j] = s1[j]; sh2[g][cq][j] = s2[j]; }
    __syncthreads();
    if (tid < 32) {
#pragma unroll
        for (int gg = 1; gg < 8; ++gg)
#pragma unroll
            for (int j = 0; j < 4; ++j) { s1[j] += sh1[gg][tid][j]; s2[j] += sh2[gg][tid][j]; }
#pragma unroll
        for (int j = 0; j < 4; ++j) {
            int c = tid * 4 + j;
            part[((size_t)blockIdx.x * FD + c) * 2] = s1[j];
            part[((size_t)blockIdx.x * FD + c) * 2 + 1] = s2[j];
        }
    }
}

// ---------------- BN stage 2: reduce NBLK chunks -> scale/shift ----------------

__global__ void __launch_bounds__(512) k_bn_stats2(const float* __restrict__ part,
                                                   const float* __restrict__ gamma,
                                                   const float* __restrict__ beta,
                                                   float* __restrict__ bnp) {
    __shared__ float sh[4][FD][2];
    int c = threadIdx.x & 127;
    int rg = threadIdx.x >> 7;
    float S1 = 0.f, S2 = 0.f;
    for (int blk = rg; blk < NBLK; blk += 4) {
        float2 p = *(const float2*)(part + ((size_t)blk * FD + c) * 2);
        S1 += p.x;
        S2 += p.y;
    }
    sh[rg][c][0] = S1;
    sh[rg][c][1] = S2;
    __syncthreads();
    if (rg == 0) {
#pragma unroll
        for (int g = 1; g < 4; ++g) { S1 += sh[g][c][0]; S2 += sh[g][c][1]; }
        float mean = S1 / (float)NN;
        float var = S2 / (float)NN - mean * mean;
        int f = c & 31;
        float scale = gamma[f] * rsqrtf(var + 1e-5f);
        bnp[c * 2] = scale;
        bnp[c * 2 + 1] = beta[f] - mean * scale;
    }
}

// ---------------- fused BN-apply + y1 GEMM (layer 0 -> plane1 + y1 bf16) ----------------

__global__ void __launch_bounds__(256) k_bn_y1(const float* __restrict__ uu,
                                               const float* __restrict__ bnp,
                                               const float* __restrict__ W1,
                                               float* __restrict__ plane,
                                               u16* __restrict__ y1) {
    __shared__ float hsT[FD][68];
    int tid = threadIdx.x;
    int nbase = blockIdx.x * 64;

    int r = tid >> 2;
    int kq = tid & 3;
    int gn = nbase + r;
    int nc = gn < NN ? gn : NN - 1;
    const float* ur = uu + ((size_t)kq * NN + nc) * CD;
#pragma unroll
    for (int q = 0; q < 8; ++q) {
        float4 v = *(const float4*)(ur + q * 4);
        int c0 = kq * CD + q * 4;
        float4 p0 = *(const float4*)(bnp + c0 * 2);
        float4 p1 = *(const float4*)(bnp + c0 * 2 + 4);
        float4 o;
        o.x = fmaxf(fmaf(v.x, p0.x, p0.y), 0.f);
        o.y = fmaxf(fmaf(v.y, p0.z, p0.w), 0.f);
        o.z = fmaxf(fmaf(v.z, p1.x, p1.y), 0.f);
        o.w = fmaxf(fmaf(v.w, p1.z, p1.w), 0.f);
        if (gn < NN) *(float4*)(plane + (size_t)gn * FD + c0) = o;
        hsT[c0 + 0][r] = o.x; hsT[c0 + 1][r] = o.y;
        hsT[c0 + 2][r] = o.z; hsT[c0 + 3][r] = o.w;
    }
    __syncthreads();

    int c0 = (tid & 31) * 4;
    int g = tid >> 5;
    int kc = c0 >> 5, jb = c0 & 31;
    float acc[8][4];
#pragma unroll
    for (int i = 0; i < 8; ++i)
#pragma unroll
        for (int j = 0; j < 4; ++j) acc[i][j] = 0.f;

    for (int m = 0; m < CD; ++m) {
        float4 wv = *(const float4*)(W1 + m * CD + jb);
        float4 xa = *(const float4*)&hsT[kc * CD + m][g * 8];
        float4 xb = *(const float4*)&hsT[kc * CD + m][g * 8 + 4];
        float xn[8] = {xa.x, xa.y, xa.z, xa.w, xb.x, xb.y, xb.z, xb.w};
#pragma unroll
        for (int i = 0; i < 8; ++i) {
            acc[i][0] += xn[i] * wv.x;
            acc[i][1] += xn[i] * wv.y;
            acc[i][2] += xn[i] * wv.z;
            acc[i][3] += xn[i] * wv.w;
        }
    }
#pragma unroll
    for (int i = 0; i < 8; ++i) {
        int n = nbase + g * 8 + i;
        if (n < NN) {
            unsigned lo = (unsigned)f2bf(acc[i][0]) | ((unsigned)f2bf(acc[i][1]) << 16);
            unsigned h2 = (unsigned)f2bf(acc[i][2]) | ((unsigned)f2bf(acc[i][3]) << 16);
            *(uint2*)(y1 + (size_t)n * FD + c0) = make_uint2(lo, h2);
        }
    }
}

// ---------------- final BN apply (layer 1 -> plane2) ----------------

__global__ void __launch_bounds__(256) k_bn_apply(const float* __restrict__ u,
                                                  const float* __restrict__ bnp,
                                                  float* __restrict__ out) {
    int gid = blockIdx.x * 256 + threadIdx.x;  // over NN*FD/4
    int n = gid >> 5;
    int q = gid & 31;
    int c0 = q * 4;
    int k = c0 >> 5, f = c0 & 31;
    float4 v = *(const float4*)(u + ((size_t)k * NN + n) * CD + f);
    float4 s0 = *(const float4*)(bnp + c0 * 2);
    float4 s1 = *(const float4*)(bnp + c0 * 2 + 4);
    float4 o;
    o.x = fmaxf(fmaf(v.x, s0.x, s0.y), 0.f);
    o.y = fmaxf(fmaf(v.y, s0.z, s0.w), 0.f);
    o.z = fmaxf(fmaf(v.z, s1.x, s1.y), 0.f);
    o.w = fmaxf(fmaf(v.w, s1.z, s1.w), 0.f);
    *(float4*)(out + (size_t)n * FD + c0) = o;
}

// ---------------- launch ----------------

extern "C" void kernel_launch(void* const* d_in, const int* in_sizes, int n_in,
                              void* d_out, int out_size, void* d_ws, size_t ws_size,
                              hipStream_t stream) {
    const float* x = (const float*)d_in[0];
    const int* ei = (const int*)d_in[1];
    const float* ew = (const float*)d_in[2];
    const float* l0W1 = (const float*)d_in[3];
    const float* l0b1 = (const float*)d_in[4];
    const float* l0W2 = (const float*)d_in[5];
    const float* l0b2 = (const float*)d_in[6];
    const float* l0g = (const float*)d_in[7];
    const float* l0be = (const float*)d_in[8];
    const float* l1W1 = (const float*)d_in[9];
    const float* l1b1 = (const float*)d_in[10];
    const float* l1W2 = (const float*)d_in[11];
    const float* l1b2 = (const float*)d_in[12];
    const float* l1g = (const float*)d_in[13];
    const float* l1be = (const float*)d_in[14];
    const float* encW = (const float*)d_in[15];
    const float* encb = (const float*)d_in[16];
    float* out = (float*)d_out;

    char* ws = (char*)d_ws;
    size_t off = 0;
    auto alloc = [&](size_t bytes) -> void* {
        void* p = ws + off;
        off += (bytes + 255) & ~(size_t)255;
        return p;
    };
    int* dcount = (int*)alloc((size_t)NN * 4);
    int* drow = (int*)alloc((size_t)(NN + 1) * 4);
    int* dcur = (int*)alloc((size_t)NN * 4);
    int* dcsum = (int*)alloc(256 * 4);
    int4* dsse = (int4*)alloc((size_t)NE * 16);
    u16* dy0 = (u16*)alloc((size_t)NN * CD * 2);            // bf16 y0 (3.2MB)
    u16* dy1 = (u16*)alloc((size_t)NN * FD * 2);            // bf16 y1 (12.8MB)
    u16* dt = (u16*)alloc((size_t)NN * FD * 2);             // bf16 t (12.8MB)
    float* du = (float*)alloc((size_t)NK * NN * CD * 4);    // u fp32 (25.6MB)
    float* dpart = (float*)alloc((size_t)NBLK * FD * 2 * 4);
    float* dbnp = (float*)alloc((size_t)FD * 2 * 4);

    const int* src = ei;
    const int* dst = ei + NE;

    // CSR build + packed (src, weights) scatter
    hipMemsetAsync(dcount, 0, (size_t)NN * 4, stream);
    k_count<<<(NE + 255) / 256, 256, 0, stream>>>(dst, dcount);
    k_chunksum<<<NCHUNK, 256, 0, stream>>>(dcount, dcsum);
    k_scan_csum<<<1, 256, 0, stream>>>(dcsum);
    k_scan_final<<<NCHUNK, 256, 0, stream>>>(dcount, dcsum, drow, dcur);
    k_scatter<<<(NE + 255) / 256, 256, 0, stream>>>(src, dst, ew, dcur, dsse);

    // plane 0 + y0
    k_enc_y0<<<(NN + 63) / 64, 256, 0, stream>>>(x, encW, encb, l0W1, out, dy0);

    // ---- layer 0 -> plane 1 ----
    float* plane1 = out + (size_t)NN * FD;
    k_aggr<CD><<<NN / 4, 256, 0, stream>>>(dy0, drow, dsse, l0b1, dt);
    k_mlp2<<<NBLK, 256, 0, stream>>>(dt, l0W2, l0b2, du, dpart);
    k_bn_stats2<<<1, 512, 0, stream>>>(dpart, l0g, l0be, dbnp);
    k_bn_y1<<<NBLK, 256, 0, stream>>>(du, dbnp, l1W1, plane1, dy1);

    // ---- layer 1 -> plane 2 ----
    float* plane2 = out + (size_t)2 * NN * FD;
    k_aggr<FD><<<NN / 4, 256, 0, stream>>>(dy1, drow, dsse, l1b1, dt);
    k_mlp2<<<NBLK, 256, 0, stream>>>(dt, l1W2, l1b2, du, dpart);
    k_bn_stats2<<<1, 512, 0, stream>>>(dpart, l1g, l1be, dbnp);
    k_bn_apply<<<(NN * FD) / 1024, 256, 0, stream>>>(du, dbnp, plane2);
}

// Round 8
// 343.659 us; speedup vs baseline: 1.2420x; 1.2420x over previous
//
#include <hip/hip_runtime.h>
#include <hip/hip_bf16.h>
#include <math.h>

#define NN 50000
#define NE 800000
#define NK 4
#define FD 128
#define CD 32
#define NCHUNK 196   // ceil(NN/256)
#define NBLK 782     // ceil(NN/64) register-GEMM blocks
#define BNCH 500     // bn stat chunks (2000 blocks total)
#define BNROWS 100   // rows per bn chunk

typedef unsigned short u16;

__device__ __forceinline__ u16 f2bf(float x) {
    union { float f; unsigned u; } c; c.f = x;
    unsigned r = c.u + 0x7fffu + ((c.u >> 16) & 1u);  // RNE
    return (u16)(r >> 16);
}
__device__ __forceinline__ float bflo(unsigned pair) {
    union { unsigned u; float f; } c; c.u = pair << 16;
    return c.f;
}
__device__ __forceinline__ float bfhi(unsigned pair) {
    union { unsigned u; float f; } c; c.u = pair & 0xffff0000u;
    return c.f;
}

// ---------------- CSR build ----------------

__global__ void k_count(const int* __restrict__ dst, int* __restrict__ count) {
    int i = blockIdx.x * 256 + threadIdx.x;
    if (i < NE) atomicAdd(&count[dst[i]], 1);
}

__global__ void k_chunksum(const int* __restrict__ count, int* __restrict__ csum) {
    __shared__ int s[256];
    int tid = threadIdx.x;
    int i = blockIdx.x * 256 + tid;
    s[tid] = (i < NN) ? count[i] : 0;
    __syncthreads();
    for (int off = 128; off > 0; off >>= 1) {
        if (tid < off) s[tid] += s[tid + off];
        __syncthreads();
    }
    if (tid == 0) csum[blockIdx.x] = s[0];
}

__global__ void k_scan_csum(int* __restrict__ csum) {
    __shared__ int s[256];
    int tid = threadIdx.x;
    int v = (tid < NCHUNK) ? csum[tid] : 0;
    s[tid] = v;
    __syncthreads();
    for (int off = 1; off < 256; off <<= 1) {
        int t = 0;
        if (tid >= off) t = s[tid - off];
        __syncthreads();
        s[tid] += t;
        __syncthreads();
    }
    if (tid < NCHUNK) csum[tid] = s[tid] - v;  // exclusive
}

__global__ void k_scan_final(const int* __restrict__ count, const int* __restrict__ csum,
                             int* __restrict__ rowstart, int* __restrict__ cursor) {
    __shared__ int s[256];
    int tid = threadIdx.x;
    int i = blockIdx.x * 256 + tid;
    int v = (i < NN) ? count[i] : 0;
    s[tid] = v;
    __syncthreads();
    for (int off = 1; off < 256; off <<= 1) {
        int t = 0;
        if (tid >= off) t = s[tid - off];
        __syncthreads();
        s[tid] += t;
        __syncthreads();
    }
    int incl = s[tid];
    int base = csum[blockIdx.x];
    int excl = base + incl - v;
    if (i < NN) {
        rowstart[i] = excl;
        cursor[i] = excl;
        if (i == NN - 1) rowstart[NN] = excl + v;
    }
}

// one packed scattered stream: {src, w01 (bf16 k0|k1), w23 (bf16 k2|k3), pad}
__global__ void k_scatter(const int* __restrict__ src, const int* __restrict__ dst,
                          const float* __restrict__ ew,
                          int* __restrict__ cursor, int4* __restrict__ sse) {
    int e = blockIdx.x * 256 + threadIdx.x;
    if (e < NE) {
        int d = dst[e];
        int p = atomicAdd(&cursor[d], 1);
        unsigned w01 = (unsigned)f2bf(ew[e]) | ((unsigned)f2bf(ew[(size_t)NE + e]) << 16);
        unsigned w23 = (unsigned)f2bf(ew[(size_t)2 * NE + e]) | ((unsigned)f2bf(ew[(size_t)3 * NE + e]) << 16);
        sse[p] = make_int4(src[e], (int)w01, (int)w23, 0);
    }
}

// ---------------- fused encoder + y0 (y0 stored bf16 [N][32]) ----------------

__global__ void __launch_bounds__(256) k_enc_y0(const float* __restrict__ x,
                                                const float* __restrict__ W,
                                                const float* __restrict__ b,
                                                const float* __restrict__ W1,
                                                float* __restrict__ out,
                                                u16* __restrict__ y0) {
    __shared__ float xsT[FD][68];
    int tid = threadIdx.x;
    int nbase = blockIdx.x * 64;

    int r = tid >> 2;
    int cg = (tid & 3) * 32;
    int gn = nbase + r;
    const float* xr = x + (size_t)(gn < NN ? gn : NN - 1) * FD;
#pragma unroll
    for (int q = 0; q < 8; ++q) {
        float4 v = *(const float4*)(xr + cg + q * 4);
        int f = cg + q * 4;
        xsT[f][r] = v.x; xsT[f + 1][r] = v.y; xsT[f + 2][r] = v.z; xsT[f + 3][r] = v.w;
    }
    __syncthreads();

    int cq = (tid & 31) * 4;
    int col = tid & 31;
    int g = tid >> 5;
    float acc[8][4];
    float acy[8];
#pragma unroll
    for (int i = 0; i < 8; ++i) {
        acy[i] = 0.f;
#pragma unroll
        for (int j = 0; j < 4; ++j) acc[i][j] = 0.f;
    }

    for (int f = 0; f < FD; ++f) {
        float4 wv = *(const float4*)(W + f * FD + cq);
        float w1 = W1[f * CD + col];
        float4 xa = *(const float4*)&xsT[f][g * 8];
        float4 xb = *(const float4*)&xsT[f][g * 8 + 4];
        float xn[8] = {xa.x, xa.y, xa.z, xa.w, xb.x, xb.y, xb.z, xb.w};
#pragma unroll
        for (int i = 0; i < 8; ++i) {
            acc[i][0] += xn[i] * wv.x;
            acc[i][1] += xn[i] * wv.y;
            acc[i][2] += xn[i] * wv.z;
            acc[i][3] += xn[i] * wv.w;
            acy[i] += xn[i] * w1;
        }
    }
    float4 bv = *(const float4*)(b + cq);
#pragma unroll
    for (int i = 0; i < 8; ++i) {
        int n = nbase + g * 8 + i;
        if (n < NN) {
            float4 o;
            o.x = acc[i][0] + bv.x;
            o.y = acc[i][1] + bv.y;
            o.z = acc[i][2] + bv.z;
            o.w = acc[i][3] + bv.w;
            *(float4*)(out + (size_t)n * FD + cq) = o;
            y0[(size_t)n * CD + col] = f2bf(acy[i]);
        }
    }
}

// ---------------- aggregation + relu -> t bf16 [N][128] ----------------
// wave = node; HALF-WAVE per edge (2 edges per pass).

template <int STRIDE>
__global__ void __launch_bounds__(256) k_aggr(const u16* __restrict__ y,
                                              const int* __restrict__ row,
                                              const int4* __restrict__ sse,
                                              const float* __restrict__ b1,
                                              u16* __restrict__ tout) {
    int tid = threadIdx.x;
    int w = tid >> 6;
    int lane = tid & 63;
    int node = blockIdx.x * 4 + w;   // NN divisible by 4

    int hi = lane >> 5;
    int sub = lane & 31;
    int k = sub >> 3;
    int fq = sub & 7;
    int f0 = fq * 4;
    int col = (STRIDE == CD) ? f0 : (k * CD + f0);
    const u16* yb = y + col;

    bool klow = k < 2;
    int lsh = (k & 1) ? 0 : 16;

    float a0 = 0.f, a1 = 0.f, a2 = 0.f, a3 = 0.f;
    int beg = row[node], end = row[node + 1];
    for (int j0 = beg; j0 < end; j0 += 8) {
        int ssv[4];
        float wwv[4];
#pragma unroll
        for (int q = 0; q < 4; ++q) {
            int jj = j0 + q * 2 + hi;
            bool ok = jj < end;
            int jc = ok ? jj : beg;
            int4 ee = sse[jc];
            ssv[q] = ee.x;
            unsigned wp = klow ? (unsigned)ee.y : (unsigned)ee.z;
            unsigned wb = (wp << lsh) & 0xffff0000u;
            union { unsigned u; float f; } cv; cv.u = wb;
            wwv[q] = ok ? cv.f : 0.f;
        }
#pragma unroll
        for (int q = 0; q < 4; ++q) {
            uint2 pv = *(const uint2*)(yb + (size_t)ssv[q] * STRIDE);
            float wq = wwv[q];
            a0 += wq * bflo(pv.x);
            a1 += wq * bfhi(pv.x);
            a2 += wq * bflo(pv.y);
            a3 += wq * bfhi(pv.y);
        }
    }
    a0 += __shfl_xor(a0, 32);
    a1 += __shfl_xor(a1, 32);
    a2 += __shfl_xor(a2, 32);
    a3 += __shfl_xor(a3, 32);

    uint2 hv = *(const uint2*)(yb + (size_t)node * STRIDE);
    float4 bv = *(const float4*)(b1 + f0);
    float t0 = fmaxf(bflo(hv.x) + a0 + bv.x, 0.f);
    float t1 = fmaxf(bfhi(hv.x) + a1 + bv.y, 0.f);
    float t2 = fmaxf(bflo(hv.y) + a2 + bv.z, 0.f);
    float t3 = fmaxf(bfhi(hv.y) + a3 + bv.w, 0.f);
    if (hi == 0) {
        unsigned lo = (unsigned)f2bf(t0) | ((unsigned)f2bf(t1) << 16);
        unsigned h2 = (unsigned)f2bf(t2) | ((unsigned)f2bf(t3) << 16);
        *(uint2*)(tout + (size_t)node * FD + k * CD + f0) = make_uint2(lo, h2);
    }
}

// ---------------- MLP2: u = t @ W2 + b2 (register GEMM, wave = community) ----------------
// thread = (k = tid>>6, node). Input row (32 bf16) in regs; W2 4KB LDS broadcast.

__global__ void __launch_bounds__(256) k_mlp2(const u16* __restrict__ t,
                                              const float* __restrict__ W2,
                                              const float* __restrict__ b2,
                                              float* __restrict__ u) {
    __shared__ float W2s[CD][CD];
    __shared__ float b2s[CD];
    int tid = threadIdx.x;
    for (int i = tid; i < CD * CD; i += 256) W2s[i >> 5][i & 31] = W2[i];
    if (tid < CD) b2s[tid] = b2[tid];
    __syncthreads();

    int k = tid >> 6;
    int node = blockIdx.x * 64 + (tid & 63);
    if (node >= NN) return;

    const uint4* tr4 = (const uint4*)(t + (size_t)node * FD + k * CD);
    float tv[32];
#pragma unroll
    for (int q = 0; q < 4; ++q) {
        uint4 v = tr4[q];
        tv[q * 8 + 0] = bflo(v.x); tv[q * 8 + 1] = bfhi(v.x);
        tv[q * 8 + 2] = bflo(v.y); tv[q * 8 + 3] = bfhi(v.y);
        tv[q * 8 + 4] = bflo(v.z); tv[q * 8 + 5] = bfhi(v.z);
        tv[q * 8 + 6] = bflo(v.w); tv[q * 8 + 7] = bfhi(v.w);
    }
    float acc[32];
#pragma unroll
    for (int j = 0; j < 32; ++j) acc[j] = b2s[j];
#pragma unroll
    for (int m = 0; m < 32; ++m) {
        float tm = tv[m];
#pragma unroll
        for (int j0 = 0; j0 < 32; j0 += 4) {
            float4 wv = *(const float4*)&W2s[m][j0];
            acc[j0 + 0] += tm * wv.x;
            acc[j0 + 1] += tm * wv.y;
            acc[j0 + 2] += tm * wv.z;
            acc[j0 + 3] += tm * wv.w;
        }
    }
    float* ur = u + ((size_t)k * NN + node) * CD;
#pragma unroll
    for (int j = 0; j < 32; j += 4) {
        float4 o = {acc[j], acc[j + 1], acc[j + 2], acc[j + 3]};
        *(float4*)(ur + j) = o;
    }
}

// ---------------- batchnorm stats (two-stage, deterministic) ----------------

__global__ void __launch_bounds__(256) k_bn_stats1(const float* __restrict__ u,
                                                   float* __restrict__ part) {
    int k = blockIdx.x & 3;
    int ch = blockIdx.x >> 2;
    int f = threadIdx.x & 31;
    int rg = threadIdx.x >> 5;
    float s1 = 0.f, s2 = 0.f;
    int nend = (ch + 1) * BNROWS;
    for (int n = ch * BNROWS + rg; n < nend; n += 8) {
        float v = u[((size_t)k * NN + n) * CD + f];
        s1 += v;
        s2 += v * v;
    }
    __shared__ float sh1[8][32], sh2[8][32];
    sh1[rg][f] = s1;
    sh2[rg][f] = s2;
    __syncthreads();
    if (rg == 0) {
#pragma unroll
        for (int r = 1; r < 8; ++r) {
            s1 += sh1[r][f];
            s2 += sh2[r][f];
        }
        part[(((size_t)k * BNCH + ch) * CD + f) * 2] = s1;
        part[(((size_t)k * BNCH + ch) * CD + f) * 2 + 1] = s2;
    }
}

__global__ void k_bn_stats2(const float* __restrict__ part, const float* __restrict__ gamma,
                            const float* __restrict__ beta, float* __restrict__ bnp) {
    int c = threadIdx.x;  // 0..127
    int k = c >> 5, f = c & 31;
    float S1 = 0.f, S2 = 0.f;
    for (int ch = 0; ch < BNCH; ++ch) {
        float2 p = *(const float2*)(part + (((size_t)k * BNCH + ch) * CD + f) * 2);
        S1 += p.x;
        S2 += p.y;
    }
    float mean = S1 / (float)NN;
    float var = S2 / (float)NN - mean * mean;
    float scale = gamma[f] * rsqrtf(var + 1e-5f);
    bnp[c * 2] = scale;
    bnp[c * 2 + 1] = beta[f] - mean * scale;
}

// ---------------- fused BN-apply + y1 (register GEMM, wave = community) ----------------
// h = relu(bn(u)) -> plane (fp32 [N][128]) and y1 = h @ W1 (bf16 [N][128])

__global__ void __launch_bounds__(256) k_bn_y1(const float* __restrict__ uu,
                                               const float* __restrict__ bnp,
                                               const float* __restrict__ W1,
                                               float* __restrict__ plane,
                                               u16* __restrict__ y1) {
    __shared__ float W1s[CD][CD];
    __shared__ float bns[FD * 2];
    int tid = threadIdx.x;
    for (int i = tid; i < CD * CD; i += 256) W1s[i >> 5][i & 31] = W1[i];
    if (tid < FD * 2 && tid >= 0) { }  // (no-op placeholder)
    if (tid < 256) { if (tid < FD * 2) bns[tid] = bnp[tid]; }
    __syncthreads();

    int k = tid >> 6;
    int node = blockIdx.x * 64 + (tid & 63);
    if (node >= NN) return;

    const float* ur = uu + ((size_t)k * NN + node) * CD;
    float hv[32];
#pragma unroll
    for (int j = 0; j < 32; j += 4) {
        float4 v = *(const float4*)(ur + j);
        int c = (k * CD + j) * 2;
        hv[j + 0] = fmaxf(fmaf(v.x, bns[c + 0], bns[c + 1]), 0.f);
        hv[j + 1] = fmaxf(fmaf(v.y, bns[c + 2], bns[c + 3]), 0.f);
        hv[j + 2] = fmaxf(fmaf(v.z, bns[c + 4], bns[c + 5]), 0.f);
        hv[j + 3] = fmaxf(fmaf(v.w, bns[c + 6], bns[c + 7]), 0.f);
    }
    float* pr = plane + (size_t)node * FD + k * CD;
#pragma unroll
    for (int j = 0; j < 32; j += 4) {
        float4 o = {hv[j], hv[j + 1], hv[j + 2], hv[j + 3]};
        *(float4*)(pr + j) = o;
    }
    float acc[32];
#pragma unroll
    for (int j = 0; j < 32; ++j) acc[j] = 0.f;
#pragma unroll
    for (int m = 0; m < 32; ++m) {
        float tm = hv[m];
#pragma unroll
        for (int j0 = 0; j0 < 32; j0 += 4) {
            float4 wv = *(const float4*)&W1s[m][j0];
            acc[j0 + 0] += tm * wv.x;
            acc[j0 + 1] += tm * wv.y;
            acc[j0 + 2] += tm * wv.z;
            acc[j0 + 3] += tm * wv.w;
        }
    }
    u16* yr = y1 + (size_t)node * FD + k * CD;
#pragma unroll
    for (int j = 0; j < 32; j += 8) {
        uint4 pk;
        pk.x = (unsigned)f2bf(acc[j + 0]) | ((unsigned)f2bf(acc[j + 1]) << 16);
        pk.y = (unsigned)f2bf(acc[j + 2]) | ((unsigned)f2bf(acc[j + 3]) << 16);
        pk.z = (unsigned)f2bf(acc[j + 4]) | ((unsigned)f2bf(acc[j + 5]) << 16);
        pk.w = (unsigned)f2bf(acc[j + 6]) | ((unsigned)f2bf(acc[j + 7]) << 16);
        *(uint4*)(yr + j) = pk;
    }
}

// ---------------- final BN apply (layer 1 -> plane2) ----------------

__global__ void __launch_bounds__(256) k_bn_apply(const float* __restrict__ u,
                                                  const float* __restrict__ bnp,
                                                  float* __restrict__ out) {
    int gid = blockIdx.x * 256 + threadIdx.x;  // over NN*FD/4
    int n = gid >> 5;
    int q = gid & 31;
    int c0 = q * 4;
    int k = c0 >> 5, f = c0 & 31;
    float4 v = *(const float4*)(u + ((size_t)k * NN + n) * CD + f);
    float4 s0 = *(const float4*)(bnp + c0 * 2);
    float4 s1 = *(const float4*)(bnp + c0 * 2 + 4);
    float4 o;
    o.x = fmaxf(fmaf(v.x, s0.x, s0.y), 0.f);
    o.y = fmaxf(fmaf(v.y, s0.z, s0.w), 0.f);
    o.z = fmaxf(fmaf(v.z, s1.x, s1.y), 0.f);
    o.w = fmaxf(fmaf(v.w, s1.z, s1.w), 0.f);
    *(float4*)(out + (size_t)n * FD + c0) = o;
}

// ---------------- launch ----------------

extern "C" void kernel_launch(void* const* d_in, const int* in_sizes, int n_in,
                              void* d_out, int out_size, void* d_ws, size_t ws_size,
                              hipStream_t stream) {
    const float* x = (const float*)d_in[0];
    const int* ei = (const int*)d_in[1];
    const float* ew = (const float*)d_in[2];
    const float* l0W1 = (const float*)d_in[3];
    const float* l0b1 = (const float*)d_in[4];
    const float* l0W2 = (const float*)d_in[5];
    const float* l0b2 = (const float*)d_in[6];
    const float* l0g = (const float*)d_in[7];
    const float* l0be = (const float*)d_in[8];
    const float* l1W1 = (const float*)d_in[9];
    const float* l1b1 = (const float*)d_in[10];
    const float* l1W2 = (const float*)d_in[11];
    const float* l1b2 = (const float*)d_in[12];
    const float* l1g = (const float*)d_in[13];
    const float* l1be = (const float*)d_in[14];
    const float* encW = (const float*)d_in[15];
    const float* encb = (const float*)d_in[16];
    float* out = (float*)d_out;

    char* ws = (char*)d_ws;
    size_t off = 0;
    auto alloc = [&](size_t bytes) -> void* {
        void* p = ws + off;
        off += (bytes + 255) & ~(size_t)255;
        return p;
    };
    int* dcount = (int*)alloc((size_t)NN * 4);
    int* drow = (int*)alloc((size_t)(NN + 1) * 4);
    int* dcur = (int*)alloc((size_t)NN * 4);
    int* dcsum = (int*)alloc(256 * 4);
    int4* dsse = (int4*)alloc((size_t)NE * 16);
    u16* dy0 = (u16*)alloc((size_t)NN * CD * 2);            // bf16 y0 (3.2MB)
    u16* dy1 = (u16*)alloc((size_t)NN * FD * 2);            // bf16 y1 (12.8MB)
    u16* dt = (u16*)alloc((size_t)NN * FD * 2);             // bf16 t (12.8MB)
    float* du = (float*)alloc((size_t)NK * NN * CD * 4);    // u fp32 (25.6MB)
    float* dpart = (float*)alloc((size_t)NK * BNCH * CD * 2 * 4);  // 512KB
    float* dbnp = (float*)alloc((size_t)FD * 2 * 4);

    const int* src = ei;
    const int* dst = ei + NE;

    // CSR build + packed (src, weights) scatter
    hipMemsetAsync(dcount, 0, (size_t)NN * 4, stream);
    k_count<<<(NE + 255) / 256, 256, 0, stream>>>(dst, dcount);
    k_chunksum<<<NCHUNK, 256, 0, stream>>>(dcount, dcsum);
    k_scan_csum<<<1, 256, 0, stream>>>(dcsum);
    k_scan_final<<<NCHUNK, 256, 0, stream>>>(dcount, dcsum, drow, dcur);
    k_scatter<<<(NE + 255) / 256, 256, 0, stream>>>(src, dst, ew, dcur, dsse);

    // plane 0 + y0
    k_enc_y0<<<(NN + 63) / 64, 256, 0, stream>>>(x, encW, encb, l0W1, out, dy0);

    // ---- layer 0 -> plane 1 ----
    float* plane1 = out + (size_t)NN * FD;
    k_aggr<CD><<<NN / 4, 256, 0, stream>>>(dy0, drow, dsse, l0b1, dt);
    k_mlp2<<<NBLK, 256, 0, stream>>>(dt, l0W2, l0b2, du);
    k_bn_stats1<<<NK * BNCH, 256, 0, stream>>>(du, dpart);
    k_bn_stats2<<<1, 128, 0, stream>>>(dpart, l0g, l0be, dbnp);
    k_bn_y1<<<NBLK, 256, 0, stream>>>(du, dbnp, l1W1, plane1, dy1);

    // ---- layer 1 -> plane 2 ----
    float* plane2 = out + (size_t)2 * NN * FD;
    k_aggr<FD><<<NN / 4, 256, 0, stream>>>(dy1, drow, dsse, l1b1, dt);
    k_mlp2<<<NBLK, 256, 0, stream>>>(dt, l1W2, l1b2, du);
    k_bn_stats1<<<NK * BNCH, 256, 0, stream>>>(du, dpart);
    k_bn_stats2<<<1, 128, 0, stream>>>(dpart, l1g, l1be, dbnp);
    k_bn_apply<<<(NN * FD) / 1024, 256, 0, stream>>>(du, dbnp, plane2);
}